// Round 1
// baseline (1043.368 us; speedup 1.0000x reference)
//
#include <hip/hip_runtime.h>

// GCN 3-layer: out = A_norm @ (A_norm @ relu(A_norm @ (X W1) + b1) W2 + b2) W3 + b3
// Strategy: counting-sort edges by dst -> CSR, then per-layer GEMM + per-node
// wave aggregation (lane = channel, float4 gathers, shfl reduce).

constexpr int SCAN_CHUNK = 1024;

__global__ void k_init_deg(int* __restrict__ deg, int n) {
    int i = blockIdx.x * blockDim.x + threadIdx.x;
    if (i < n) deg[i] = 1;   // self-loop
}

__global__ void k_hist(const int* __restrict__ dst, int E, int* __restrict__ deg) {
    int stride = gridDim.x * blockDim.x;
    for (int i = blockIdx.x * blockDim.x + threadIdx.x; i < E; i += stride)
        atomicAdd(&deg[dst[i]], 1);
}

__global__ void k_dinv(const int* __restrict__ deg, float* __restrict__ dinv, int n) {
    int i = blockIdx.x * blockDim.x + threadIdx.x;
    if (i < n) dinv[i] = rsqrtf((float)deg[i]);
}

// ---- exclusive scan of counts[n] -> offsets[0..n], cursor copy ----
__global__ void k_scan1(const int* __restrict__ counts, int n, int* __restrict__ csum) {
    __shared__ int lds[256];
    int base = blockIdx.x * SCAN_CHUNK;
    int t = threadIdx.x;
    int s = 0;
#pragma unroll
    for (int j = 0; j < 4; j++) {
        int idx = base + t * 4 + j;
        if (idx < n) s += counts[idx];
    }
    lds[t] = s;
    __syncthreads();
    for (int st = 128; st > 0; st >>= 1) {
        if (t < st) lds[t] += lds[t + st];
        __syncthreads();
    }
    if (t == 0) csum[blockIdx.x] = lds[0];
}

__global__ void k_scan2(const int* __restrict__ csum, int nchunk,
                        int* __restrict__ coff, int* __restrict__ offsets, int n) {
    if (threadIdx.x == 0 && blockIdx.x == 0) {
        int acc = 0;
        for (int i = 0; i < nchunk; i++) { coff[i] = acc; acc += csum[i]; }
        offsets[n] = acc;
    }
}

__global__ void k_scan3(const int* __restrict__ counts, int n, const int* __restrict__ coff,
                        int* __restrict__ offsets, int* __restrict__ cursor) {
    __shared__ int lds[256];
    int base = blockIdx.x * SCAN_CHUNK;
    int t = threadIdx.x;
    int c[4];
    int tsum = 0;
#pragma unroll
    for (int j = 0; j < 4; j++) {
        int idx = base + t * 4 + j;
        c[j] = (idx < n) ? counts[idx] : 0;
        tsum += c[j];
    }
    lds[t] = tsum;
    __syncthreads();
    for (int st = 1; st < 256; st <<= 1) {
        int v = (t >= st) ? lds[t - st] : 0;
        __syncthreads();
        lds[t] += v;
        __syncthreads();
    }
    int run = (t ? lds[t - 1] : 0) + coff[blockIdx.x];
#pragma unroll
    for (int j = 0; j < 4; j++) {
        int idx = base + t * 4 + j;
        if (idx < n) { offsets[idx] = run; cursor[idx] = run; run += c[j]; }
    }
}

__global__ void k_scatter(const int* __restrict__ src, const int* __restrict__ dst, int E, int n,
                          const float* __restrict__ dinv, int* __restrict__ cursor,
                          int* __restrict__ ssrc, float* __restrict__ snorm) {
    int total = E + n;
    int stride = gridDim.x * blockDim.x;
    for (int i = blockIdx.x * blockDim.x + threadIdx.x; i < total; i += stride) {
        int s, d;
        if (i < E) { s = src[i]; d = dst[i]; } else { s = d = i - E; }
        int pos = atomicAdd(&cursor[d], 1);
        ssrc[pos] = s;
        snorm[pos] = dinv[s] * dinv[d];
    }
}

// ---- GEMM: Y[n,64] = X[n,K] @ W[K,64] ----
template <int K>
__global__ void k_gemm64(const float* __restrict__ X, const float* __restrict__ W,
                         float* __restrict__ Y, int n) {
    __shared__ float ws[K * 64];
    __shared__ float xs[16 * K];
    int t = threadIdx.x;
    for (int i = t; i < K * 64; i += 256) ws[i] = W[i];
    int nb = blockIdx.x * 16;
    for (int i = t; i < 16 * K; i += 256) {
        int r = i / K, c = i % K;
        int node = nb + r;
        xs[i] = (node < n) ? X[(size_t)node * K + c] : 0.f;
    }
    __syncthreads();
    int col = t & 63, grp = t >> 6;
    float acc[4] = {0.f, 0.f, 0.f, 0.f};
    for (int k = 0; k < K; k++) {
        float w = ws[k * 64 + col];
#pragma unroll
        for (int i = 0; i < 4; i++) acc[i] += xs[(grp * 4 + i) * K + k] * w;
    }
#pragma unroll
    for (int i = 0; i < 4; i++) {
        int node = nb + grp * 4 + i;
        if (node < n) Y[(size_t)node * 64 + col] = acc[i];
    }
}

// ---- GEMM: Y[n,10] = X[n,64] @ W[64,10] ----
__global__ void k_gemm10(const float* __restrict__ X, const float* __restrict__ W,
                         float* __restrict__ Y, int n) {
    __shared__ float ws[64 * 10];
    __shared__ float xs[16 * 64];
    int t = threadIdx.x;
    for (int i = t; i < 640; i += 256) ws[i] = W[i];
    int nb = blockIdx.x * 16;
    for (int i = t; i < 16 * 64; i += 256) {
        int r = i >> 6, c = i & 63;
        int node = nb + r;
        xs[i] = (node < n) ? X[(size_t)node * 64 + c] : 0.f;
    }
    __syncthreads();
    int ns = t >> 4, c = t & 15;
    if (c < 10) {
        float acc = 0.f;
        for (int k = 0; k < 64; k++) acc += xs[ns * 64 + k] * ws[k * 10 + c];
        int node = nb + ns;
        if (node < n) Y[(size_t)node * 10 + c] = acc;
    }
}

// ---- aggregation, 64 channels: out[n] = (relu?)(sum_e norm*H[src] + bias) ----
__global__ void k_agg64(const float* __restrict__ H, const int* __restrict__ off,
                        const int* __restrict__ ssrc, const float* __restrict__ snorm,
                        const float* __restrict__ bias, float* __restrict__ out,
                        int n, int relu) {
    int wid = blockIdx.x * 4 + (threadIdx.x >> 6);
    if (wid >= n) return;
    int lane = threadIdx.x & 63;
    int s0 = off[wid], s1 = off[wid + 1];
    int esub = lane >> 4;
    int coff = (lane & 15) << 2;
    float ax = 0.f, ay = 0.f, az = 0.f, aw = 0.f;
    for (int e = s0 + esub; e < s1; e += 4) {
        int s = ssrc[e];
        float nrm = snorm[e];
        const float4 v = *reinterpret_cast<const float4*>(H + (size_t)s * 64 + coff);
        ax += nrm * v.x; ay += nrm * v.y; az += nrm * v.z; aw += nrm * v.w;
    }
    ax += __shfl_xor(ax, 16); ay += __shfl_xor(ay, 16);
    az += __shfl_xor(az, 16); aw += __shfl_xor(aw, 16);
    ax += __shfl_xor(ax, 32); ay += __shfl_xor(ay, 32);
    az += __shfl_xor(az, 32); aw += __shfl_xor(aw, 32);
    if (lane < 16) {
        ax += bias[coff + 0]; ay += bias[coff + 1];
        az += bias[coff + 2]; aw += bias[coff + 3];
        if (relu) {
            ax = fmaxf(ax, 0.f); ay = fmaxf(ay, 0.f);
            az = fmaxf(az, 0.f); aw = fmaxf(aw, 0.f);
        }
        float4 r = {ax, ay, az, aw};
        *reinterpret_cast<float4*>(out + (size_t)wid * 64 + coff) = r;
    }
}

// ---- aggregation, 10 channels (final layer, no relu) ----
__global__ void k_agg10(const float* __restrict__ H, const int* __restrict__ off,
                        const int* __restrict__ ssrc, const float* __restrict__ snorm,
                        const float* __restrict__ bias, float* __restrict__ out, int n) {
    int wid = blockIdx.x * 4 + (threadIdx.x >> 6);
    if (wid >= n) return;
    int lane = threadIdx.x & 63;
    int s0 = off[wid], s1 = off[wid + 1];
    int esub = lane >> 4, c = lane & 15;
    float acc = 0.f;
    if (c < 10) {
        for (int e = s0 + esub; e < s1; e += 4)
            acc += snorm[e] * H[(size_t)ssrc[e] * 10 + c];
    }
    acc += __shfl_xor(acc, 16);
    acc += __shfl_xor(acc, 32);
    if (lane < 16 && c < 10) out[(size_t)wid * 10 + c] = acc + bias[c];
}

extern "C" void kernel_launch(void* const* d_in, const int* in_sizes, int n_in,
                              void* d_out, int out_size, void* d_ws, size_t ws_size,
                              hipStream_t stream) {
    const float* x  = (const float*)d_in[0];
    const int*   ei = (const int*)d_in[1];
    const float* W1 = (const float*)d_in[2];
    const float* b1 = (const float*)d_in[3];
    const float* W2 = (const float*)d_in[4];
    const float* b2 = (const float*)d_in[5];
    const float* W3 = (const float*)d_in[6];
    const float* b3 = (const float*)d_in[7];

    int N = in_sizes[0] / 128;
    int E = in_sizes[1] / 2;
    const int* esrc = ei;
    const int* edst = ei + E;

    char* p = (char*)d_ws;
    auto carve = [&](size_t bytes) -> void* {
        void* r = p;
        p += (bytes + 255) & ~(size_t)255;
        return r;
    };
    int*   deg     = (int*)carve((size_t)N * 4);
    float* dinv    = (float*)carve((size_t)N * 4);
    int*   offsets = (int*)carve((size_t)(N + 1) * 4);
    int*   cursor  = (int*)carve((size_t)N * 4);
    int*   csum    = (int*)carve(512 * 4);
    int*   coff    = (int*)carve(512 * 4);
    int*   ssrc    = (int*)carve((size_t)(E + N) * 4);
    float* snorm   = (float*)carve((size_t)(E + N) * 4);
    float* F       = (float*)carve((size_t)N * 64 * 4);
    float* G       = (float*)carve((size_t)N * 64 * 4);
    (void)ws_size; (void)n_in; (void)out_size;

    int nchunk = (N + SCAN_CHUNK - 1) / SCAN_CHUNK;

    k_init_deg<<<(N + 255) / 256, 256, 0, stream>>>(deg, N);
    k_hist<<<2048, 256, 0, stream>>>(edst, E, deg);
    k_dinv<<<(N + 255) / 256, 256, 0, stream>>>(deg, dinv, N);
    k_scan1<<<nchunk, 256, 0, stream>>>(deg, N, csum);
    k_scan2<<<1, 64, 0, stream>>>(csum, nchunk, coff, offsets, N);
    k_scan3<<<nchunk, 256, 0, stream>>>(deg, N, coff, offsets, cursor);
    k_scatter<<<2048, 256, 0, stream>>>(esrc, edst, E, N, dinv, cursor, ssrc, snorm);

    // layer 1: F = X @ W1 ; G = relu(Agg(F) + b1)
    k_gemm64<128><<<(N + 15) / 16, 256, 0, stream>>>(x, W1, F, N);
    k_agg64<<<(N + 3) / 4, 256, 0, stream>>>(F, offsets, ssrc, snorm, b1, G, N, 1);
    // layer 2: F = G @ W2 ; G = relu(Agg(F) + b2)
    k_gemm64<64><<<(N + 15) / 16, 256, 0, stream>>>(G, W2, F, N);
    k_agg64<<<(N + 3) / 4, 256, 0, stream>>>(F, offsets, ssrc, snorm, b2, G, N, 1);
    // layer 3: F = G @ W3 ; out = Agg(F) + b3
    k_gemm10<<<(N + 15) / 16, 256, 0, stream>>>(G, W3, F, N);
    k_agg10<<<(N + 3) / 4, 256, 0, stream>>>(F, offsets, ssrc, snorm, b3, (float*)d_out, N);
}

// Round 2
// 730.772 us; speedup vs baseline: 1.4278x; 1.4278x over previous
//
#include <hip/hip_runtime.h>

// GCN 3-layer. v2: counting-sort CSR + bf16 gather tables for the 64-ch
// aggregations (halves the random-gather traffic that dominates).

constexpr int SCAN_CHUNK = 1024;

__device__ __forceinline__ unsigned short f2bf(float f) {
    unsigned int u = __builtin_bit_cast(unsigned int, f);
    u += 0x7FFF + ((u >> 16) & 1);          // round to nearest even
    return (unsigned short)(u >> 16);
}
__device__ __forceinline__ float bf_lo(unsigned int d) {
    return __builtin_bit_cast(float, d << 16);
}
__device__ __forceinline__ float bf_hi(unsigned int d) {
    return __builtin_bit_cast(float, d & 0xFFFF0000u);
}

__global__ void k_init_deg(int* __restrict__ deg, int n) {
    int i = blockIdx.x * blockDim.x + threadIdx.x;
    if (i < n) deg[i] = 1;   // self-loop
}

__global__ void k_hist(const int* __restrict__ dst, int E, int* __restrict__ deg) {
    int stride = gridDim.x * blockDim.x;
    for (int i = blockIdx.x * blockDim.x + threadIdx.x; i < E; i += stride)
        atomicAdd(&deg[dst[i]], 1);
}

__global__ void k_dinv(const int* __restrict__ deg, float* __restrict__ dinv, int n) {
    int i = blockIdx.x * blockDim.x + threadIdx.x;
    if (i < n) dinv[i] = rsqrtf((float)deg[i]);
}

__global__ void k_scan1(const int* __restrict__ counts, int n, int* __restrict__ csum) {
    __shared__ int lds[256];
    int base = blockIdx.x * SCAN_CHUNK;
    int t = threadIdx.x;
    int s = 0;
#pragma unroll
    for (int j = 0; j < 4; j++) {
        int idx = base + t * 4 + j;
        if (idx < n) s += counts[idx];
    }
    lds[t] = s;
    __syncthreads();
    for (int st = 128; st > 0; st >>= 1) {
        if (t < st) lds[t] += lds[t + st];
        __syncthreads();
    }
    if (t == 0) csum[blockIdx.x] = lds[0];
}

__global__ void k_scan2(const int* __restrict__ csum, int nchunk,
                        int* __restrict__ coff, int* __restrict__ offsets, int n) {
    if (threadIdx.x == 0 && blockIdx.x == 0) {
        int acc = 0;
        for (int i = 0; i < nchunk; i++) { coff[i] = acc; acc += csum[i]; }
        offsets[n] = acc;
    }
}

__global__ void k_scan3(const int* __restrict__ counts, int n, const int* __restrict__ coff,
                        int* __restrict__ offsets, int* __restrict__ cursor) {
    __shared__ int lds[256];
    int base = blockIdx.x * SCAN_CHUNK;
    int t = threadIdx.x;
    int c[4];
    int tsum = 0;
#pragma unroll
    for (int j = 0; j < 4; j++) {
        int idx = base + t * 4 + j;
        c[j] = (idx < n) ? counts[idx] : 0;
        tsum += c[j];
    }
    lds[t] = tsum;
    __syncthreads();
    for (int st = 1; st < 256; st <<= 1) {
        int v = (t >= st) ? lds[t - st] : 0;
        __syncthreads();
        lds[t] += v;
        __syncthreads();
    }
    int run = (t ? lds[t - 1] : 0) + coff[blockIdx.x];
#pragma unroll
    for (int j = 0; j < 4; j++) {
        int idx = base + t * 4 + j;
        if (idx < n) { offsets[idx] = run; cursor[idx] = run; run += c[j]; }
    }
}

__global__ void k_scatter(const int* __restrict__ src, const int* __restrict__ dst, int E, int n,
                          const float* __restrict__ dinv, int* __restrict__ cursor,
                          int* __restrict__ ssrc, float* __restrict__ snorm) {
    int total = E + n;
    int stride = gridDim.x * blockDim.x;
    for (int i = blockIdx.x * blockDim.x + threadIdx.x; i < total; i += stride) {
        int s, d;
        if (i < E) { s = src[i]; d = dst[i]; } else { s = d = i - E; }
        int pos = atomicAdd(&cursor[d], 1);
        ssrc[pos] = s;
        snorm[pos] = dinv[s] * dinv[d];
    }
}

// ---- GEMM: Y_bf16[n,64] = X[n,K] @ W[K,64], packed bf16 output ----
template <int K>
__global__ void k_gemm64bf(const float* __restrict__ X, const float* __restrict__ W,
                           unsigned short* __restrict__ Y, int n) {
    __shared__ float ws[K * 64];
    __shared__ float xs[16 * K];
    int t = threadIdx.x;
    for (int i = t; i < K * 64; i += 256) ws[i] = W[i];
    int nb = blockIdx.x * 16;
    for (int i = t; i < 16 * K; i += 256) {
        int r = i / K, c = i % K;
        int node = nb + r;
        xs[i] = (node < n) ? X[(size_t)node * K + c] : 0.f;
    }
    __syncthreads();
    int node = t >> 4;            // 0..15
    int ch0  = (t & 15) * 4;      // 0,4,...,60
    float ax = 0.f, ay = 0.f, az = 0.f, aw = 0.f;
    for (int k = 0; k < K; k++) {
        float xv = xs[node * K + k];
        const float4 w = *reinterpret_cast<const float4*>(&ws[k * 64 + ch0]);
        ax += xv * w.x; ay += xv * w.y; az += xv * w.z; aw += xv * w.w;
    }
    int gn = nb + node;
    if (gn < n) {
        ushort4 r;
        r.x = f2bf(ax); r.y = f2bf(ay); r.z = f2bf(az); r.w = f2bf(aw);
        *reinterpret_cast<ushort4*>(Y + (size_t)gn * 64 + ch0) = r;
    }
}

// ---- GEMM: Y[n,10] = X[n,64] @ W[64,10] (f32) ----
__global__ void k_gemm10(const float* __restrict__ X, const float* __restrict__ W,
                         float* __restrict__ Y, int n) {
    __shared__ float ws[64 * 10];
    __shared__ float xs[16 * 64];
    int t = threadIdx.x;
    for (int i = t; i < 640; i += 256) ws[i] = W[i];
    int nb = blockIdx.x * 16;
    for (int i = t; i < 16 * 64; i += 256) {
        int r = i >> 6, c = i & 63;
        int node = nb + r;
        xs[i] = (node < n) ? X[(size_t)node * 64 + c] : 0.f;
    }
    __syncthreads();
    int ns = t >> 4, c = t & 15;
    if (c < 10) {
        float acc = 0.f;
        for (int k = 0; k < 64; k++) acc += xs[ns * 64 + k] * ws[k * 10 + c];
        int node = nb + ns;
        if (node < n) Y[(size_t)node * 10 + c] = acc;
    }
}

// ---- aggregation, 64 bf16 channels: out_f32 = (relu?)(sum norm*H[src] + b) ----
// wave per node; lane = (edge-slot 0..7) x (channel-group 0..7); 16B gathers.
__global__ void k_agg64bf(const unsigned short* __restrict__ H, const int* __restrict__ off,
                          const int* __restrict__ ssrc, const float* __restrict__ snorm,
                          const float* __restrict__ bias, float* __restrict__ out,
                          int n, int relu) {
    int wid = blockIdx.x * 4 + (threadIdx.x >> 6);
    if (wid >= n) return;
    int lane = threadIdx.x & 63;
    int s0 = off[wid], s1 = off[wid + 1];
    int esub = lane >> 3;        // 0..7 edge slot
    int cg   = lane & 7;         // channel group -> channels cg*8 .. cg*8+7
    float a0 = 0.f, a1 = 0.f, a2 = 0.f, a3 = 0.f;
    float a4 = 0.f, a5 = 0.f, a6 = 0.f, a7 = 0.f;
    for (int e = s0 + esub; e < s1; e += 8) {
        int s = ssrc[e];
        float nrm = snorm[e];
        const uint4 v = *reinterpret_cast<const uint4*>(H + (size_t)s * 64 + cg * 8);
        a0 += nrm * bf_lo(v.x); a1 += nrm * bf_hi(v.x);
        a2 += nrm * bf_lo(v.y); a3 += nrm * bf_hi(v.y);
        a4 += nrm * bf_lo(v.z); a5 += nrm * bf_hi(v.z);
        a6 += nrm * bf_lo(v.w); a7 += nrm * bf_hi(v.w);
    }
#pragma unroll
    for (int m = 8; m <= 32; m <<= 1) {
        a0 += __shfl_xor(a0, m); a1 += __shfl_xor(a1, m);
        a2 += __shfl_xor(a2, m); a3 += __shfl_xor(a3, m);
        a4 += __shfl_xor(a4, m); a5 += __shfl_xor(a5, m);
        a6 += __shfl_xor(a6, m); a7 += __shfl_xor(a7, m);
    }
    if (esub == 0) {
        const float* b = bias + cg * 8;
        a0 += b[0]; a1 += b[1]; a2 += b[2]; a3 += b[3];
        a4 += b[4]; a5 += b[5]; a6 += b[6]; a7 += b[7];
        if (relu) {
            a0 = fmaxf(a0, 0.f); a1 = fmaxf(a1, 0.f);
            a2 = fmaxf(a2, 0.f); a3 = fmaxf(a3, 0.f);
            a4 = fmaxf(a4, 0.f); a5 = fmaxf(a5, 0.f);
            a6 = fmaxf(a6, 0.f); a7 = fmaxf(a7, 0.f);
        }
        float4 r0 = {a0, a1, a2, a3}, r1 = {a4, a5, a6, a7};
        float* o = out + (size_t)wid * 64 + cg * 8;
        *reinterpret_cast<float4*>(o)     = r0;
        *reinterpret_cast<float4*>(o + 4) = r1;
    }
}

// ---- aggregation, 10 f32 channels (final, no relu) ----
__global__ void k_agg10(const float* __restrict__ H, const int* __restrict__ off,
                        const int* __restrict__ ssrc, const float* __restrict__ snorm,
                        const float* __restrict__ bias, float* __restrict__ out, int n) {
    int wid = blockIdx.x * 4 + (threadIdx.x >> 6);
    if (wid >= n) return;
    int lane = threadIdx.x & 63;
    int s0 = off[wid], s1 = off[wid + 1];
    int esub = lane >> 4, c = lane & 15;
    float acc = 0.f;
    if (c < 10) {
        for (int e = s0 + esub; e < s1; e += 4)
            acc += snorm[e] * H[(size_t)ssrc[e] * 10 + c];
    }
    acc += __shfl_xor(acc, 16);
    acc += __shfl_xor(acc, 32);
    if (lane < 16 && c < 10) out[(size_t)wid * 10 + c] = acc + bias[c];
}

extern "C" void kernel_launch(void* const* d_in, const int* in_sizes, int n_in,
                              void* d_out, int out_size, void* d_ws, size_t ws_size,
                              hipStream_t stream) {
    const float* x  = (const float*)d_in[0];
    const int*   ei = (const int*)d_in[1];
    const float* W1 = (const float*)d_in[2];
    const float* b1 = (const float*)d_in[3];
    const float* W2 = (const float*)d_in[4];
    const float* b2 = (const float*)d_in[5];
    const float* W3 = (const float*)d_in[6];
    const float* b3 = (const float*)d_in[7];

    int N = in_sizes[0] / 128;
    int E = in_sizes[1] / 2;
    const int* esrc = ei;
    const int* edst = ei + E;

    char* p = (char*)d_ws;
    auto carve = [&](size_t bytes) -> void* {
        void* r = p;
        p += (bytes + 255) & ~(size_t)255;
        return r;
    };
    int*   deg     = (int*)carve((size_t)N * 4);
    float* dinv    = (float*)carve((size_t)N * 4);
    int*   offsets = (int*)carve((size_t)(N + 1) * 4);
    int*   cursor  = (int*)carve((size_t)N * 4);
    int*   csum    = (int*)carve(512 * 4);
    int*   coff    = (int*)carve(512 * 4);
    int*   ssrc    = (int*)carve((size_t)(E + N) * 4);
    float* snorm   = (float*)carve((size_t)(E + N) * 4);
    unsigned short* Fb = (unsigned short*)carve((size_t)N * 64 * 2);  // bf16 table
    float* F10     = (float*)carve((size_t)N * 64 * 4);               // f32 (gemm10 out reuses)
    float* G       = (float*)carve((size_t)N * 64 * 4);
    (void)ws_size; (void)n_in; (void)out_size;

    int nchunk = (N + SCAN_CHUNK - 1) / SCAN_CHUNK;

    k_init_deg<<<(N + 255) / 256, 256, 0, stream>>>(deg, N);
    k_hist<<<2048, 256, 0, stream>>>(edst, E, deg);
    k_dinv<<<(N + 255) / 256, 256, 0, stream>>>(deg, dinv, N);
    k_scan1<<<nchunk, 256, 0, stream>>>(deg, N, csum);
    k_scan2<<<1, 64, 0, stream>>>(csum, nchunk, coff, offsets, N);
    k_scan3<<<nchunk, 256, 0, stream>>>(deg, N, coff, offsets, cursor);
    k_scatter<<<2048, 256, 0, stream>>>(esrc, edst, E, N, dinv, cursor, ssrc, snorm);

    // layer 1: Fb = bf16(X @ W1) ; G = relu(Agg(Fb) + b1)
    k_gemm64bf<128><<<(N + 15) / 16, 256, 0, stream>>>(x, W1, Fb, N);
    k_agg64bf<<<(N + 3) / 4, 256, 0, stream>>>(Fb, offsets, ssrc, snorm, b1, G, N, 1);
    // layer 2: Fb = bf16(G @ W2) ; G2 -> reuse F10... use G as input, write to F10? keep distinct:
    k_gemm64bf<64><<<(N + 15) / 16, 256, 0, stream>>>(G, W2, Fb, N);
    k_agg64bf<<<(N + 3) / 4, 256, 0, stream>>>(Fb, offsets, ssrc, snorm, b2, F10, N, 1);
    // layer 3: G10 = F10 @ W3 ; out = Agg(G10) + b3   (reuse G buffer for 10-ch)
    k_gemm10<<<(N + 15) / 16, 256, 0, stream>>>(F10, W3, G, N);
    k_agg10<<<(N + 3) / 4, 256, 0, stream>>>(G, offsets, ssrc, snorm, b3, (float*)d_out, N);
}

// Round 3
// 634.536 us; speedup vs baseline: 1.6443x; 1.1517x over previous
//
#include <hip/hip_runtime.h>

// GCN 3-layer. v3: merged 8B edge records {src, norm} (one random line-touch
// per edge in the counting-sort scatter), one-thread-per-edge scatter.

constexpr int SCAN_CHUNK = 1024;

__device__ __forceinline__ unsigned short f2bf(float f) {
    unsigned int u = __builtin_bit_cast(unsigned int, f);
    u += 0x7FFF + ((u >> 16) & 1);          // round to nearest even
    return (unsigned short)(u >> 16);
}
__device__ __forceinline__ float bf_lo(unsigned int d) {
    return __builtin_bit_cast(float, d << 16);
}
__device__ __forceinline__ float bf_hi(unsigned int d) {
    return __builtin_bit_cast(float, d & 0xFFFF0000u);
}

__global__ void k_init_deg(int* __restrict__ deg, int n) {
    int i = blockIdx.x * blockDim.x + threadIdx.x;
    if (i < n) deg[i] = 1;   // self-loop
}

__global__ void k_hist(const int* __restrict__ dst, int E, int* __restrict__ deg) {
    int stride = gridDim.x * blockDim.x;
    for (int i = blockIdx.x * blockDim.x + threadIdx.x; i < E; i += stride)
        atomicAdd(&deg[dst[i]], 1);
}

__global__ void k_dinv(const int* __restrict__ deg, float* __restrict__ dinv, int n) {
    int i = blockIdx.x * blockDim.x + threadIdx.x;
    if (i < n) dinv[i] = rsqrtf((float)deg[i]);
}

__global__ void k_scan1(const int* __restrict__ counts, int n, int* __restrict__ csum) {
    __shared__ int lds[256];
    int base = blockIdx.x * SCAN_CHUNK;
    int t = threadIdx.x;
    int s = 0;
#pragma unroll
    for (int j = 0; j < 4; j++) {
        int idx = base + t * 4 + j;
        if (idx < n) s += counts[idx];
    }
    lds[t] = s;
    __syncthreads();
    for (int st = 128; st > 0; st >>= 1) {
        if (t < st) lds[t] += lds[t + st];
        __syncthreads();
    }
    if (t == 0) csum[blockIdx.x] = lds[0];
}

__global__ void k_scan2(const int* __restrict__ csum, int nchunk,
                        int* __restrict__ coff, int* __restrict__ offsets, int n) {
    if (threadIdx.x == 0 && blockIdx.x == 0) {
        int acc = 0;
        for (int i = 0; i < nchunk; i++) { coff[i] = acc; acc += csum[i]; }
        offsets[n] = acc;
    }
}

__global__ void k_scan3(const int* __restrict__ counts, int n, const int* __restrict__ coff,
                        int* __restrict__ offsets, int* __restrict__ cursor) {
    __shared__ int lds[256];
    int base = blockIdx.x * SCAN_CHUNK;
    int t = threadIdx.x;
    int c[4];
    int tsum = 0;
#pragma unroll
    for (int j = 0; j < 4; j++) {
        int idx = base + t * 4 + j;
        c[j] = (idx < n) ? counts[idx] : 0;
        tsum += c[j];
    }
    lds[t] = tsum;
    __syncthreads();
    for (int st = 1; st < 256; st <<= 1) {
        int v = (t >= st) ? lds[t - st] : 0;
        __syncthreads();
        lds[t] += v;
        __syncthreads();
    }
    int run = (t ? lds[t - 1] : 0) + coff[blockIdx.x];
#pragma unroll
    for (int j = 0; j < 4; j++) {
        int idx = base + t * 4 + j;
        if (idx < n) { offsets[idx] = run; cursor[idx] = run; run += c[j]; }
    }
}

// one thread per (edge or self-loop); single 8B record store per edge
__global__ void k_scatter(const int* __restrict__ src, const int* __restrict__ dst, int E, int n,
                          const float* __restrict__ dinv, int* __restrict__ cursor,
                          uint2* __restrict__ sedge) {
    int i = blockIdx.x * blockDim.x + threadIdx.x;
    if (i >= E + n) return;
    int s, d;
    if (i < E) { s = src[i]; d = dst[i]; } else { s = d = i - E; }
    float nrm = dinv[s] * dinv[d];
    int pos = atomicAdd(&cursor[d], 1);
    uint2 rec;
    rec.x = (unsigned)s;
    rec.y = __builtin_bit_cast(unsigned, nrm);
    sedge[pos] = rec;
}

// ---- GEMM: Y_bf16[n,64] = X[n,K] @ W[K,64], packed bf16 output ----
template <int K>
__global__ void k_gemm64bf(const float* __restrict__ X, const float* __restrict__ W,
                           unsigned short* __restrict__ Y, int n) {
    __shared__ float ws[K * 64];
    __shared__ float xs[16 * K];
    int t = threadIdx.x;
    for (int i = t; i < K * 64; i += 256) ws[i] = W[i];
    int nb = blockIdx.x * 16;
    for (int i = t; i < 16 * K; i += 256) {
        int r = i / K, c = i % K;
        int node = nb + r;
        xs[i] = (node < n) ? X[(size_t)node * K + c] : 0.f;
    }
    __syncthreads();
    int node = t >> 4;            // 0..15
    int ch0  = (t & 15) * 4;      // 0,4,...,60
    float ax = 0.f, ay = 0.f, az = 0.f, aw = 0.f;
    for (int k = 0; k < K; k++) {
        float xv = xs[node * K + k];
        const float4 w = *reinterpret_cast<const float4*>(&ws[k * 64 + ch0]);
        ax += xv * w.x; ay += xv * w.y; az += xv * w.z; aw += xv * w.w;
    }
    int gn = nb + node;
    if (gn < n) {
        ushort4 r;
        r.x = f2bf(ax); r.y = f2bf(ay); r.z = f2bf(az); r.w = f2bf(aw);
        *reinterpret_cast<ushort4*>(Y + (size_t)gn * 64 + ch0) = r;
    }
}

// ---- GEMM: Y[n,10] = X[n,64] @ W[64,10] (f32) ----
__global__ void k_gemm10(const float* __restrict__ X, const float* __restrict__ W,
                         float* __restrict__ Y, int n) {
    __shared__ float ws[64 * 10];
    __shared__ float xs[16 * 64];
    int t = threadIdx.x;
    for (int i = t; i < 640; i += 256) ws[i] = W[i];
    int nb = blockIdx.x * 16;
    for (int i = t; i < 16 * 64; i += 256) {
        int r = i >> 6, c = i & 63;
        int node = nb + r;
        xs[i] = (node < n) ? X[(size_t)node * 64 + c] : 0.f;
    }
    __syncthreads();
    int ns = t >> 4, c = t & 15;
    if (c < 10) {
        float acc = 0.f;
        for (int k = 0; k < 64; k++) acc += xs[ns * 64 + k] * ws[k * 10 + c];
        int node = nb + ns;
        if (node < n) Y[(size_t)node * 10 + c] = acc;
    }
}

// ---- aggregation, 64 bf16 channels: out_f32 = (relu?)(sum norm*H[src] + b) ----
__global__ void k_agg64bf(const unsigned short* __restrict__ H, const int* __restrict__ off,
                          const uint2* __restrict__ sedge,
                          const float* __restrict__ bias, float* __restrict__ out,
                          int n, int relu) {
    int wid = blockIdx.x * 4 + (threadIdx.x >> 6);
    if (wid >= n) return;
    int lane = threadIdx.x & 63;
    int s0 = off[wid], s1 = off[wid + 1];
    int esub = lane >> 3;        // 0..7 edge slot
    int cg   = lane & 7;         // channel group -> channels cg*8 .. cg*8+7
    float a0 = 0.f, a1 = 0.f, a2 = 0.f, a3 = 0.f;
    float a4 = 0.f, a5 = 0.f, a6 = 0.f, a7 = 0.f;
    for (int e = s0 + esub; e < s1; e += 8) {
        uint2 rec = sedge[e];
        int s = (int)rec.x;
        float nrm = __builtin_bit_cast(float, rec.y);
        const uint4 v = *reinterpret_cast<const uint4*>(H + (size_t)s * 64 + cg * 8);
        a0 += nrm * bf_lo(v.x); a1 += nrm * bf_hi(v.x);
        a2 += nrm * bf_lo(v.y); a3 += nrm * bf_hi(v.y);
        a4 += nrm * bf_lo(v.z); a5 += nrm * bf_hi(v.z);
        a6 += nrm * bf_lo(v.w); a7 += nrm * bf_hi(v.w);
    }
#pragma unroll
    for (int m = 8; m <= 32; m <<= 1) {
        a0 += __shfl_xor(a0, m); a1 += __shfl_xor(a1, m);
        a2 += __shfl_xor(a2, m); a3 += __shfl_xor(a3, m);
        a4 += __shfl_xor(a4, m); a5 += __shfl_xor(a5, m);
        a6 += __shfl_xor(a6, m); a7 += __shfl_xor(a7, m);
    }
    if (esub == 0) {
        const float* b = bias + cg * 8;
        a0 += b[0]; a1 += b[1]; a2 += b[2]; a3 += b[3];
        a4 += b[4]; a5 += b[5]; a6 += b[6]; a7 += b[7];
        if (relu) {
            a0 = fmaxf(a0, 0.f); a1 = fmaxf(a1, 0.f);
            a2 = fmaxf(a2, 0.f); a3 = fmaxf(a3, 0.f);
            a4 = fmaxf(a4, 0.f); a5 = fmaxf(a5, 0.f);
            a6 = fmaxf(a6, 0.f); a7 = fmaxf(a7, 0.f);
        }
        float4 r0 = {a0, a1, a2, a3}, r1 = {a4, a5, a6, a7};
        float* o = out + (size_t)wid * 64 + cg * 8;
        *reinterpret_cast<float4*>(o)     = r0;
        *reinterpret_cast<float4*>(o + 4) = r1;
    }
}

// ---- aggregation, 10 f32 channels (final, no relu) ----
__global__ void k_agg10(const float* __restrict__ H, const int* __restrict__ off,
                        const uint2* __restrict__ sedge,
                        const float* __restrict__ bias, float* __restrict__ out, int n) {
    int wid = blockIdx.x * 4 + (threadIdx.x >> 6);
    if (wid >= n) return;
    int lane = threadIdx.x & 63;
    int s0 = off[wid], s1 = off[wid + 1];
    int esub = lane >> 4, c = lane & 15;
    float acc = 0.f;
    if (c < 10) {
        for (int e = s0 + esub; e < s1; e += 4) {
            uint2 rec = sedge[e];
            acc += __builtin_bit_cast(float, rec.y) * H[(size_t)rec.x * 10 + c];
        }
    }
    acc += __shfl_xor(acc, 16);
    acc += __shfl_xor(acc, 32);
    if (lane < 16 && c < 10) out[(size_t)wid * 10 + c] = acc + bias[c];
}

extern "C" void kernel_launch(void* const* d_in, const int* in_sizes, int n_in,
                              void* d_out, int out_size, void* d_ws, size_t ws_size,
                              hipStream_t stream) {
    const float* x  = (const float*)d_in[0];
    const int*   ei = (const int*)d_in[1];
    const float* W1 = (const float*)d_in[2];
    const float* b1 = (const float*)d_in[3];
    const float* W2 = (const float*)d_in[4];
    const float* b2 = (const float*)d_in[5];
    const float* W3 = (const float*)d_in[6];
    const float* b3 = (const float*)d_in[7];

    int N = in_sizes[0] / 128;
    int E = in_sizes[1] / 2;
    const int* esrc = ei;
    const int* edst = ei + E;

    char* p = (char*)d_ws;
    auto carve = [&](size_t bytes) -> void* {
        void* r = p;
        p += (bytes + 255) & ~(size_t)255;
        return r;
    };
    int*   deg     = (int*)carve((size_t)N * 4);
    float* dinv    = (float*)carve((size_t)N * 4);
    int*   offsets = (int*)carve((size_t)(N + 1) * 4);
    int*   cursor  = (int*)carve((size_t)N * 4);
    int*   csum    = (int*)carve(512 * 4);
    int*   coff    = (int*)carve(512 * 4);
    uint2* sedge   = (uint2*)carve((size_t)(E + N) * 8);
    unsigned short* Fb = (unsigned short*)carve((size_t)N * 64 * 2);  // bf16 table
    float* F10     = (float*)carve((size_t)N * 64 * 4);
    float* G       = (float*)carve((size_t)N * 64 * 4);
    (void)ws_size; (void)n_in; (void)out_size;

    int nchunk = (N + SCAN_CHUNK - 1) / SCAN_CHUNK;

    k_init_deg<<<(N + 255) / 256, 256, 0, stream>>>(deg, N);
    k_hist<<<2048, 256, 0, stream>>>(edst, E, deg);
    k_dinv<<<(N + 255) / 256, 256, 0, stream>>>(deg, dinv, N);
    k_scan1<<<nchunk, 256, 0, stream>>>(deg, N, csum);
    k_scan2<<<1, 64, 0, stream>>>(csum, nchunk, coff, offsets, N);
    k_scan3<<<nchunk, 256, 0, stream>>>(deg, N, coff, offsets, cursor);
    k_scatter<<<(E + N + 255) / 256, 256, 0, stream>>>(esrc, edst, E, N, dinv, cursor, sedge);

    // layer 1: Fb = bf16(X @ W1) ; G = relu(Agg(Fb) + b1)
    k_gemm64bf<128><<<(N + 15) / 16, 256, 0, stream>>>(x, W1, Fb, N);
    k_agg64bf<<<(N + 3) / 4, 256, 0, stream>>>(Fb, offsets, sedge, b1, G, N, 1);
    // layer 2
    k_gemm64bf<64><<<(N + 15) / 16, 256, 0, stream>>>(G, W2, Fb, N);
    k_agg64bf<<<(N + 3) / 4, 256, 0, stream>>>(Fb, offsets, sedge, b2, F10, N, 1);
    // layer 3
    k_gemm10<<<(N + 15) / 16, 256, 0, stream>>>(F10, W3, G, N);
    k_agg10<<<(N + 3) / 4, 256, 0, stream>>>(G, offsets, sedge, b3, (float*)d_out, N);
}